// Round 4
// baseline (5114.016 us; speedup 1.0000x reference)
//
#include <hip/hip_runtime.h>
#include <hip/hip_bf16.h>

#define HID 128
#define NEG 0.2f
#define LN_EPS 1e-5f
#define NG 16

static __device__ __forceinline__ float leaky(float x) { return x > 0.f ? x : NEG * x; }

// monotone float -> uint key for atomicMax (handles negatives)
static __device__ __forceinline__ unsigned fkey(float f) {
  unsigned u = __float_as_uint(f);
  return (u & 0x80000000u) ? ~u : (u | 0x80000000u);
}
static __device__ __forceinline__ float fdec(unsigned k) {
  unsigned u = (k & 0x80000000u) ? (k & 0x7fffffffu) : ~k;
  return __uint_as_float(u);
}
// edge accessors; self-loops are virtual edges e in [E, E+N)
static __device__ __forceinline__ int esrc(const int* ei, int E, int e) { return e < E ? ei[e] : e - E; }
static __device__ __forceinline__ int edst(const int* ei, int E, int e) { return e < E ? ei[E + e] : e - E; }

// h[n][c] = sum_k x[n][k] * W[k][c]
__global__ __launch_bounds__(256) void k_lin(const float* __restrict__ x, const float* __restrict__ W,
                                             float* __restrict__ h, int N) {
  int idx = blockIdx.x * 256 + threadIdx.x;
  if (idx >= N * HID) return;
  int n = idx >> 7, c = idx & 127;
  float acc = 0.f;
  for (int k = 0; k < HID; ++k) acc = fmaf(x[n * HID + k], W[k * HID + c], acc);
  h[idx] = acc;
}

// as_[n][hh] = sum_d h[n][hh*32+d]*a_src[hh*32+d]; ad_ likewise
__global__ __launch_bounds__(256) void k_alpha(const float* __restrict__ h, const float* __restrict__ a_s,
                                               const float* __restrict__ a_d, float* __restrict__ as_,
                                               float* __restrict__ ad_, int N) {
  int idx = blockIdx.x * 256 + threadIdx.x;
  if (idx >= N * 4) return;
  int n = idx >> 2, hh = idx & 3;
  float s = 0.f, d = 0.f;
  for (int j = 0; j < 32; ++j) {
    float v = h[n * HID + hh * 32 + j];
    s = fmaf(v, a_s[hh * 32 + j], s);
    d = fmaf(v, a_d[hh * 32 + j], d);
  }
  as_[idx] = s;
  ad_[idx] = d;
}

// segment_max of leaky(as[src]+ad[dst]) into key[dst][head]
__global__ __launch_bounds__(256) void k_emax(const int* __restrict__ ei, int E, int ET,
                                              const float* __restrict__ as_, const float* __restrict__ ad_,
                                              unsigned* __restrict__ key) {
  int e = blockIdx.x * 256 + threadIdx.x;
  if (e >= ET) return;
  int s = esrc(ei, E, e), d = edst(ei, E, e);
  for (int hh = 0; hh < 4; ++hh) {
    float v = leaky(as_[s * 4 + hh] + ad_[d * 4 + hh]);
    atomicMax(&key[d * 4 + hh], fkey(v));
  }
}

// segment_sum of exp(e - emax[dst]) into den[dst][head]
__global__ __launch_bounds__(256) void k_denom(const int* __restrict__ ei, int E, int ET,
                                               const float* __restrict__ as_, const float* __restrict__ ad_,
                                               const unsigned* __restrict__ key, float* __restrict__ den) {
  int e = blockIdx.x * 256 + threadIdx.x;
  if (e >= ET) return;
  int s = esrc(ei, E, e), d = edst(ei, E, e);
  for (int hh = 0; hh < 4; ++hh) {
    float v = leaky(as_[s * 4 + hh] + ad_[d * 4 + hh]);
    atomicAdd(&den[d * 4 + hh], expf(v - fdec(key[d * 4 + hh])));
  }
}

// one wave per edge: agg[dst][c] += exp(e-emax)*h[src][c]
__global__ __launch_bounds__(256) void k_agg(const int* __restrict__ ei, int E, int ET,
                                             const float* __restrict__ as_, const float* __restrict__ ad_,
                                             const unsigned* __restrict__ key, const float* __restrict__ h,
                                             float* __restrict__ agg) {
  int wv = (blockIdx.x * 256 + threadIdx.x) >> 6;
  int lane = threadIdx.x & 63;
  if (wv >= ET) return;
  int s = esrc(ei, E, wv), d = edst(ei, E, wv);
  int hh = lane >> 4, c0 = lane * 2;
  float v = leaky(as_[s * 4 + hh] + ad_[d * 4 + hh]);
  float ex = expf(v - fdec(key[d * 4 + hh]));
  float2 hs = *(const float2*)&h[(size_t)s * HID + c0];
  atomicAdd(&agg[(size_t)d * HID + c0], ex * hs.x);
  atomicAdd(&agg[(size_t)d * HID + c0 + 1], ex * hs.y);
}

// per-node: normalize, +bias, LayerNorm, ELU. In-place on agg.
__global__ __launch_bounds__(128) void k_epi(float* __restrict__ agg, const float* __restrict__ den,
                                             const float* __restrict__ b, const float* __restrict__ g,
                                             const float* __restrict__ be, int N) {
  __shared__ float red[128];
  int n = blockIdx.x, c = threadIdx.x;
  float val = agg[(size_t)n * HID + c] / den[n * 4 + (c >> 5)] + b[c];
  red[c] = val;
  __syncthreads();
  for (int off = 64; off; off >>= 1) {
    if (c < off) red[c] += red[c + off];
    __syncthreads();
  }
  float mu = red[0] * (1.f / HID);
  __syncthreads();
  float dd = val - mu;
  red[c] = dd * dd;
  __syncthreads();
  for (int off = 64; off; off >>= 1) {
    if (c < off) red[c] += red[c + off];
    __syncthreads();
  }
  float rstd = rsqrtf(red[0] * (1.f / HID) + LN_EPS);
  float y = dd * rstd * g[c] + be[c];
  agg[(size_t)n * HID + c] = y > 0.f ? y : expm1f(y);
}

__global__ __launch_bounds__(256) void k_cnt(const int* __restrict__ bat, int* __restrict__ gcnt, int N) {
  int n = blockIdx.x * 256 + threadIdx.x;
  if (n < N) atomicAdd(&gcnt[bat[n]], 1);
}

__global__ __launch_bounds__(256) void k_gsum(const float* __restrict__ xb, const int* __restrict__ bat,
                                              float* __restrict__ gsum, int N) {
  int idx = blockIdx.x * 256 + threadIdx.x;
  if (idx >= N * HID) return;
  int n = idx >> 7, c = idx & 127;
  atomicAdd(&gsum[bat[n] * HID + c], xb[idx]);
}

// fp32 output: [N, 256] = [x | g_global[batch]]
__global__ __launch_bounds__(256) void k_out(const float* __restrict__ xb, const int* __restrict__ bat,
                                             const float* __restrict__ gsum, const int* __restrict__ gcnt,
                                             float* __restrict__ out, int N) {
  int idx = blockIdx.x * 256 + threadIdx.x;
  if (idx >= N * HID) return;
  int n = idx >> 7, c = idx & 127;
  int b = bat[n];
  out[(size_t)n * 256 + c] = xb[idx];
  out[(size_t)n * 256 + 128 + c] = gsum[b * HID + c] / fmaxf((float)gcnt[b], 1.f);
}

extern "C" void kernel_launch(void* const* d_in, const int* in_sizes, int n_in,
                              void* d_out, int out_size, void* d_ws, size_t ws_size,
                              hipStream_t stream) {
  const float* x   = (const float*)d_in[0];
  const int*   ei  = (const int*)d_in[1];
  const int*   bat = (const int*)d_in[2];
  const float* W1  = (const float*)d_in[3];
  const float* as1 = (const float*)d_in[4];
  const float* ad1 = (const float*)d_in[5];
  const float* b1  = (const float*)d_in[6];
  const float* g1  = (const float*)d_in[7];
  const float* be1 = (const float*)d_in[8];
  const float* W2  = (const float*)d_in[9];
  const float* as2 = (const float*)d_in[10];
  const float* ad2 = (const float*)d_in[11];
  const float* b2  = (const float*)d_in[12];
  const float* g2  = (const float*)d_in[13];
  const float* be2 = (const float*)d_in[14];
  int N = in_sizes[0] / HID;
  int E = in_sizes[1] / 2;
  int ET = E + N;  // with self-loops

  char* p = (char*)d_ws;
  auto alloc = [&](size_t bytes) {
    void* r = (void*)p;
    p += (bytes + 255) & ~(size_t)255;
    return r;
  };
  float*    h    = (float*)alloc((size_t)N * HID * 4);
  float*    agg  = (float*)alloc((size_t)N * HID * 4);  // also holds layer outputs (in-place epi)
  float*    asb  = (float*)alloc((size_t)N * 4 * 4);
  float*    adb  = (float*)alloc((size_t)N * 4 * 4);
  unsigned* key  = (unsigned*)alloc((size_t)N * 4 * 4);
  float*    den  = (float*)alloc((size_t)N * 4 * 4);
  float*    gsum = (float*)alloc((size_t)NG * HID * 4);
  int*      gcnt = (int*)alloc((size_t)NG * 4);

  int gNC = (N * HID + 255) / 256;   // thread per (n,c)
  int gNH = (N * 4 + 255) / 256;     // thread per (n,head)
  int gE  = (ET + 255) / 256;        // thread per edge
  int gEW = (ET * 64 + 255) / 256;   // wave per edge
  int gN  = (N + 255) / 256;

  // ---- layer 1 ----
  k_lin<<<gNC, 256, 0, stream>>>(x, W1, h, N);
  k_alpha<<<gNH, 256, 0, stream>>>(h, as1, ad1, asb, adb, N);
  hipMemsetAsync(key, 0, (size_t)N * 16, stream);
  hipMemsetAsync(den, 0, (size_t)N * 16, stream);
  hipMemsetAsync(agg, 0, (size_t)N * HID * 4, stream);
  k_emax<<<gE, 256, 0, stream>>>(ei, E, ET, asb, adb, key);
  k_denom<<<gE, 256, 0, stream>>>(ei, E, ET, asb, adb, key, den);
  k_agg<<<gEW, 256, 0, stream>>>(ei, E, ET, asb, adb, key, h, agg);
  k_epi<<<N, 128, 0, stream>>>(agg, den, b1, g1, be1, N);

  // ---- layer 2 (input = agg, i.e. layer-1 output) ----
  k_lin<<<gNC, 256, 0, stream>>>(agg, W2, h, N);
  k_alpha<<<gNH, 256, 0, stream>>>(h, as2, ad2, asb, adb, N);
  hipMemsetAsync(key, 0, (size_t)N * 16, stream);
  hipMemsetAsync(den, 0, (size_t)N * 16, stream);
  hipMemsetAsync(agg, 0, (size_t)N * HID * 4, stream);  // ordered after k_lin consumed it
  k_emax<<<gE, 256, 0, stream>>>(ei, E, ET, asb, adb, key);
  k_denom<<<gE, 256, 0, stream>>>(ei, E, ET, asb, adb, key, den);
  k_agg<<<gEW, 256, 0, stream>>>(ei, E, ET, asb, adb, key, h, agg);
  k_epi<<<N, 128, 0, stream>>>(agg, den, b2, g2, be2, N);

  // ---- readout ----
  hipMemsetAsync(gsum, 0, (size_t)NG * HID * 4, stream);
  hipMemsetAsync(gcnt, 0, (size_t)NG * 4, stream);
  k_cnt<<<gN, 256, 0, stream>>>(bat, gcnt, N);
  k_gsum<<<gNC, 256, 0, stream>>>(agg, bat, gsum, N);
  k_out<<<gNC, 256, 0, stream>>>(agg, bat, gsum, gcnt, (float*)d_out, N);
}

// Round 5
// 662.439 us; speedup vs baseline: 7.7200x; 7.7200x over previous
//
#include <hip/hip_runtime.h>
#include <hip/hip_bf16.h>

#define HID 128
#define NEG 0.2f
#define LN_EPS 1e-5f
#define NG 16

static __device__ __forceinline__ float leaky(float x) { return x > 0.f ? x : NEG * x; }

// ---------------- CSR build ----------------
__global__ __launch_bounds__(256) void k_edge_count(const int* __restrict__ ei, int E,
                                                    int* __restrict__ deg) {
  for (int e = blockIdx.x * blockDim.x + threadIdx.x; e < E; e += gridDim.x * blockDim.x)
    atomicAdd(&deg[ei[E + e]], 1);
}

__global__ __launch_bounds__(1024) void k_scan_a(const int* __restrict__ deg, int* __restrict__ offs,
                                                 int* __restrict__ part, int N) {
  __shared__ int s[1024];
  int i = blockIdx.x * 1024 + threadIdx.x;
  int v = (i < N) ? deg[i] : 0;
  s[threadIdx.x] = v;
  __syncthreads();
  for (int d = 1; d < 1024; d <<= 1) {
    int t = (threadIdx.x >= d) ? s[threadIdx.x - d] : 0;
    __syncthreads();
    s[threadIdx.x] += t;
    __syncthreads();
  }
  if (i < N) offs[i + 1] = s[threadIdx.x];
  if (threadIdx.x == 1023) part[blockIdx.x] = s[1023];
}

__global__ __launch_bounds__(1024) void k_scan_b(int* __restrict__ part, int nb) {
  __shared__ int s[1024];
  int v = (threadIdx.x < nb) ? part[threadIdx.x] : 0;
  s[threadIdx.x] = v;
  __syncthreads();
  for (int d = 1; d < 1024; d <<= 1) {
    int t = (threadIdx.x >= d) ? s[threadIdx.x - d] : 0;
    __syncthreads();
    s[threadIdx.x] += t;
    __syncthreads();
  }
  if (threadIdx.x < nb) part[threadIdx.x] = (threadIdx.x == 0) ? 0 : s[threadIdx.x - 1];
}

__global__ __launch_bounds__(256) void k_scan_c(int* __restrict__ offs, const int* __restrict__ part, int N) {
  int i = blockIdx.x * blockDim.x + threadIdx.x;
  if (i < N) offs[i + 1] += part[i >> 10];
  if (i == 0) offs[0] = 0;
}

__global__ __launch_bounds__(256) void k_edge_fill(const int* __restrict__ ei, int E,
                                                   const int* __restrict__ offs,
                                                   int* __restrict__ cursor, int* __restrict__ csr) {
  for (int e = blockIdx.x * blockDim.x + threadIdx.x; e < E; e += gridDim.x * blockDim.x) {
    int d = ei[E + e];
    int slot = atomicAdd(&cursor[d], 1);
    csr[offs[d] + slot] = ei[e];
  }
}

// ---------------- h = x @ W, alpha_s/alpha_d fused ----------------
// 4 waves/block, W staged in 64KB LDS, one row per wave per iter.
__global__ __launch_bounds__(256) void k_gemm_alpha(const float* __restrict__ xin, const float* __restrict__ W,
                                                    const float* __restrict__ a_src, const float* __restrict__ a_dst,
                                                    float* __restrict__ h, float* __restrict__ as_out,
                                                    float* __restrict__ ad_out, int N, int iters) {
  __shared__ float Ws[HID * HID];
  __shared__ float xrow[4][HID];
  int t = threadIdx.x;
  for (int i = t * 4; i < HID * HID; i += 1024) *(float4*)&Ws[i] = *(const float4*)&W[i];
  int wave = t >> 6, lane = t & 63;
  int c0 = lane * 2, c1 = c0 + 1, head = lane >> 4;
  float as0 = a_src[c0], as1 = a_src[c1], ad0 = a_dst[c0], ad1 = a_dst[c1];
  __syncthreads();
  for (int it = 0; it < iters; ++it) {
    int r = (it * gridDim.x + blockIdx.x) * 4 + wave;
    if (r < N) {
      float2 xv = *(const float2*)&xin[(size_t)r * HID + c0];
      xrow[wave][c0] = xv.x;
      xrow[wave][c1] = xv.y;
    }
    __syncthreads();
    if (r < N) {
      float acc0 = 0.f, acc1 = 0.f;
#pragma unroll 8
      for (int k = 0; k < HID; ++k) {
        float xk = xrow[wave][k];
        float2 wv = *(const float2*)&Ws[k * HID + c0];
        acc0 = fmaf(xk, wv.x, acc0);
        acc1 = fmaf(xk, wv.y, acc1);
      }
      float ps = acc0 * as0 + acc1 * as1;
      float pd = acc0 * ad0 + acc1 * ad1;
#pragma unroll
      for (int msk = 1; msk < 16; msk <<= 1) {
        ps += __shfl_xor(ps, msk);
        pd += __shfl_xor(pd, msk);
      }
      if ((lane & 15) == 0) {
        as_out[r * 4 + head] = ps;
        ad_out[r * 4 + head] = pd;
      }
      *(float2*)&h[(size_t)r * HID + c0] = make_float2(acc0, acc1);
    }
    __syncthreads();
  }
}

// ---------------- per-dst softmax + aggregation + LN + ELU (one wave per dst) ----------------
__global__ __launch_bounds__(256) void k_gat_agg(const int* __restrict__ offs, const int* __restrict__ csr,
                                                 const float* __restrict__ as, const float* __restrict__ ad,
                                                 const float* __restrict__ h, const float* __restrict__ bias,
                                                 const float* __restrict__ gam, const float* __restrict__ bet,
                                                 float* __restrict__ out, int N) {
  int wave = threadIdx.x >> 6, lane = threadIdx.x & 63;
  int dst = blockIdx.x * 4 + wave;
  if (dst >= N) return;
  int c0 = lane * 2, c1 = c0 + 1, head = lane >> 4;
  const float4 ad4 = *(const float4*)&ad[dst * 4];
  const float4 asf = *(const float4*)&as[dst * 4];
  // self-loop logits
  float e0 = leaky(asf.x + ad4.x), e1 = leaky(asf.y + ad4.y);
  float e2 = leaky(asf.z + ad4.z), e3 = leaky(asf.w + ad4.w);
  float m0 = e0, m1 = e1, m2 = e2, m3 = e3;
  int beg = offs[dst], end = offs[dst + 1];
  // pass 1: per-head max, lane-parallel over edges
  for (int i = beg + lane; i < end; i += 64) {
    int s = csr[i];
    float4 s4 = *(const float4*)&as[s * 4];
    m0 = fmaxf(m0, leaky(s4.x + ad4.x));
    m1 = fmaxf(m1, leaky(s4.y + ad4.y));
    m2 = fmaxf(m2, leaky(s4.z + ad4.z));
    m3 = fmaxf(m3, leaky(s4.w + ad4.w));
  }
#pragma unroll
  for (int msk = 1; msk < 64; msk <<= 1) {
    m0 = fmaxf(m0, __shfl_xor(m0, msk));
    m1 = fmaxf(m1, __shfl_xor(m1, msk));
    m2 = fmaxf(m2, __shfl_xor(m2, msk));
    m3 = fmaxf(m3, __shfl_xor(m3, msk));
  }
  float mh  = (head == 0) ? m0 : (head == 1) ? m1 : (head == 2) ? m2 : m3;
  float adh = (head == 0) ? ad4.x : (head == 1) ? ad4.y : (head == 2) ? ad4.z : ad4.w;
  float esf = (head == 0) ? e0 : (head == 1) ? e1 : (head == 2) ? e2 : e3;
  // pass 2: unnormalized aggregation (self-loop first), normalize at end
  float p = __expf(esf - mh);
  float ssum = p;
  float2 hv = *(const float2*)&h[(size_t)dst * HID + c0];
  float acc0 = p * hv.x, acc1 = p * hv.y;
  for (int base = beg; base < end; base += 64) {
    int idx = base + lane;
    int my = (idx < end) ? csr[idx] : 0;
    int cnt = min(64, end - base);
    for (int j = 0; j < cnt; ++j) {
      int s = __shfl(my, j);
      float e = leaky(as[s * 4 + head] + adh);
      float pp = __expf(e - mh);
      ssum += pp;
      float2 hs = *(const float2*)&h[(size_t)s * HID + c0];
      acc0 = fmaf(pp, hs.x, acc0);
      acc1 = fmaf(pp, hs.y, acc1);
    }
  }
  float inv = 1.f / ssum;
  acc0 = acc0 * inv + bias[c0];
  acc1 = acc1 * inv + bias[c1];
  // fused LayerNorm (wave reduction, 2 ch/lane) + ELU
  float sum = acc0 + acc1;
#pragma unroll
  for (int msk = 1; msk < 64; msk <<= 1) sum += __shfl_xor(sum, msk);
  float mu = sum * (1.f / HID);
  float d0 = acc0 - mu, d1 = acc1 - mu;
  float vv = d0 * d0 + d1 * d1;
#pragma unroll
  for (int msk = 1; msk < 64; msk <<= 1) vv += __shfl_xor(vv, msk);
  float rstd = rsqrtf(vv * (1.f / HID) + LN_EPS);
  float y0 = d0 * rstd * gam[c0] + bet[c0];
  float y1 = d1 * rstd * gam[c1] + bet[c1];
  y0 = y0 > 0.f ? y0 : expm1f(y0);
  y1 = y1 > 0.f ? y1 : expm1f(y1);
  *(float2*)&out[(size_t)dst * HID + c0] = make_float2(y0, y1);
}

// ---------------- per-graph mean readout ----------------
__global__ __launch_bounds__(256) void k_graph_sum(const float* __restrict__ x, const int* __restrict__ bat,
                                                   float* __restrict__ gsum, float* __restrict__ gcnt, int N) {
  __shared__ float ls[NG * HID];
  __shared__ float lc[NG];
  for (int i = threadIdx.x; i < NG * HID; i += 256) ls[i] = 0.f;
  if (threadIdx.x < NG) lc[threadIdx.x] = 0.f;
  __syncthreads();
  int wave = threadIdx.x >> 6, lane = threadIdx.x & 63;
  for (int n = blockIdx.x * 4 + wave; n < N; n += gridDim.x * 4) {
    int b = bat[n];
    float2 v = *(const float2*)&x[(size_t)n * HID + lane * 2];
    atomicAdd(&ls[b * HID + lane * 2], v.x);
    atomicAdd(&ls[b * HID + lane * 2 + 1], v.y);
    if (lane == 0) atomicAdd(&lc[b], 1.f);
  }
  __syncthreads();
  for (int i = threadIdx.x; i < NG * HID; i += 256) atomicAdd(&gsum[i], ls[i]);
  if (threadIdx.x < NG) atomicAdd(&gcnt[threadIdx.x], lc[threadIdx.x]);
}

// fp32 output: [N, 256] = [x | g_global[batch]]
__global__ __launch_bounds__(256) void k_concat_out(const float* __restrict__ x, const int* __restrict__ bat,
                                                    const float* __restrict__ gsum, const float* __restrict__ gcnt,
                                                    float* __restrict__ out, int N) {
  int total = N * (HID / 4);
  for (int idx = blockIdx.x * blockDim.x + threadIdx.x; idx < total; idx += gridDim.x * blockDim.x) {
    int n = idx >> 5, q = idx & 31;
    int c = q * 4;
    float4 xv = *(const float4*)&x[(size_t)n * HID + c];
    int b = bat[n];
    float rin = 1.f / fmaxf(gcnt[b], 1.f);
    float4 gv = *(const float4*)&gsum[b * HID + c];
    *(float4*)&out[(size_t)n * 256 + c] = xv;
    *(float4*)&out[(size_t)n * 256 + 128 + c] =
        make_float4(gv.x * rin, gv.y * rin, gv.z * rin, gv.w * rin);
  }
}

extern "C" void kernel_launch(void* const* d_in, const int* in_sizes, int n_in,
                              void* d_out, int out_size, void* d_ws, size_t ws_size,
                              hipStream_t stream) {
  const float* x   = (const float*)d_in[0];
  const int*   ei  = (const int*)d_in[1];
  const int*   bat = (const int*)d_in[2];
  const float* W1  = (const float*)d_in[3];
  const float* as1 = (const float*)d_in[4];
  const float* ad1 = (const float*)d_in[5];
  const float* b1  = (const float*)d_in[6];
  const float* g1  = (const float*)d_in[7];
  const float* be1 = (const float*)d_in[8];
  const float* W2  = (const float*)d_in[9];
  const float* as2 = (const float*)d_in[10];
  const float* ad2 = (const float*)d_in[11];
  const float* b2  = (const float*)d_in[12];
  const float* g2  = (const float*)d_in[13];
  const float* be2 = (const float*)d_in[14];
  int N = in_sizes[0] / HID;
  int E = in_sizes[1] / 2;

  char* p = (char*)d_ws;
  auto alloc = [&](size_t bytes) {
    void* r = (void*)p;
    p += (bytes + 255) & ~(size_t)255;
    return r;
  };
  int*   deg   = (int*)alloc((size_t)N * 4);      // also reused as fill cursor
  int*   offs  = (int*)alloc((size_t)(N + 1) * 4);
  int    nsb   = (N + 1023) / 1024;
  int*   part  = (int*)alloc((size_t)nsb * 4);
  int*   csr   = (int*)alloc((size_t)E * 4);
  float* h     = (float*)alloc((size_t)N * HID * 4);
  float* asb   = (float*)alloc((size_t)N * 4 * 4);
  float* adb   = (float*)alloc((size_t)N * 4 * 4);
  float* xb    = (float*)alloc((size_t)N * HID * 4);
  float* gsum  = (float*)alloc((size_t)NG * HID * 4);
  float* gcnt  = (float*)alloc((size_t)NG * 4);

  hipMemsetAsync(deg, 0, (size_t)N * 4, stream);
  hipMemsetAsync(gsum, 0, (size_t)NG * HID * 4, stream);
  hipMemsetAsync(gcnt, 0, (size_t)NG * 4, stream);

  int egrid = (E + 255) / 256;
  if (egrid > 2048) egrid = 2048;
  k_edge_count<<<egrid, 256, 0, stream>>>(ei, E, deg);
  k_scan_a<<<nsb, 1024, 0, stream>>>(deg, offs, part, N);
  k_scan_b<<<1, 1024, 0, stream>>>(part, nsb);
  k_scan_c<<<(N + 255) / 256, 256, 0, stream>>>(offs, part, N);
  hipMemsetAsync(deg, 0, (size_t)N * 4, stream);  // cursor
  k_edge_fill<<<egrid, 256, 0, stream>>>(ei, E, offs, deg, csr);

  int ggrid = 512;
  int iters = (N + ggrid * 4 - 1) / (ggrid * 4);
  int agrid = (N + 3) / 4;

  k_gemm_alpha<<<ggrid, 256, 0, stream>>>(x, W1, as1, ad1, h, asb, adb, N, iters);
  k_gat_agg<<<agrid, 256, 0, stream>>>(offs, csr, asb, adb, h, b1, g1, be1, xb, N);
  k_gemm_alpha<<<ggrid, 256, 0, stream>>>(xb, W2, as2, ad2, h, asb, adb, N, iters);
  k_gat_agg<<<agrid, 256, 0, stream>>>(offs, csr, asb, adb, h, b2, g2, be2, xb, N);

  k_graph_sum<<<256, 256, 0, stream>>>(xb, bat, gsum, gcnt, N);
  int cgrid = (N * (HID / 4) + 255) / 256;
  if (cgrid > 4096) cgrid = 4096;
  k_concat_out<<<cgrid, 256, 0, stream>>>(xb, bat, gsum, gcnt, (float*)d_out, N);
}

// Round 6
// 655.081 us; speedup vs baseline: 7.8067x; 1.0112x over previous
//
#include <hip/hip_runtime.h>
#include <hip/hip_bf16.h>

#define HID 128
#define NEG 0.2f
#define LN_EPS 1e-5f
#define NG 16

static __device__ __forceinline__ float leaky(float x) { return x > 0.f ? x : NEG * x; }

static __device__ __forceinline__ unsigned pack_bf2(float a, float b) {
  __hip_bfloat16 ha = __float2bfloat16(a), hb = __float2bfloat16(b);
  unsigned ua = *reinterpret_cast<unsigned short*>(&ha);
  unsigned ub = *reinterpret_cast<unsigned short*>(&hb);
  return ua | (ub << 16);
}

// ---------------- CSR build ----------------
__global__ __launch_bounds__(256) void k_edge_count(const int* __restrict__ ei, int E,
                                                    int* __restrict__ deg) {
  for (int e = blockIdx.x * blockDim.x + threadIdx.x; e < E; e += gridDim.x * blockDim.x)
    atomicAdd(&deg[ei[E + e]], 1);
}

__global__ __launch_bounds__(1024) void k_scan_a(const int* __restrict__ deg, int* __restrict__ offs,
                                                 int* __restrict__ part, int N) {
  __shared__ int s[1024];
  int i = blockIdx.x * 1024 + threadIdx.x;
  int v = (i < N) ? deg[i] : 0;
  s[threadIdx.x] = v;
  __syncthreads();
  for (int d = 1; d < 1024; d <<= 1) {
    int t = (threadIdx.x >= d) ? s[threadIdx.x - d] : 0;
    __syncthreads();
    s[threadIdx.x] += t;
    __syncthreads();
  }
  if (i < N) offs[i + 1] = s[threadIdx.x];
  if (threadIdx.x == 1023) part[blockIdx.x] = s[1023];
}

__global__ __launch_bounds__(1024) void k_scan_b(int* __restrict__ part, int nb) {
  __shared__ int s[1024];
  int v = (threadIdx.x < nb) ? part[threadIdx.x] : 0;
  s[threadIdx.x] = v;
  __syncthreads();
  for (int d = 1; d < 1024; d <<= 1) {
    int t = (threadIdx.x >= d) ? s[threadIdx.x - d] : 0;
    __syncthreads();
    s[threadIdx.x] += t;
    __syncthreads();
  }
  if (threadIdx.x < nb) part[threadIdx.x] = (threadIdx.x == 0) ? 0 : s[threadIdx.x - 1];
}

__global__ __launch_bounds__(256) void k_scan_c(int* __restrict__ offs, const int* __restrict__ part, int N) {
  int i = blockIdx.x * blockDim.x + threadIdx.x;
  if (i < N) offs[i + 1] += part[i >> 10];
  if (i == 0) offs[0] = 0;
}

__global__ __launch_bounds__(256) void k_edge_fill(const int* __restrict__ ei, int E,
                                                   const int* __restrict__ offs,
                                                   int* __restrict__ cursor, int* __restrict__ csr) {
  for (int e = blockIdx.x * blockDim.x + threadIdx.x; e < E; e += gridDim.x * blockDim.x) {
    int d = ei[E + e];
    int slot = atomicAdd(&cursor[d], 1);
    csr[offs[d] + slot] = ei[e];
  }
}

// ---------------- h = x @ W (bf16-packed out), alpha_s/alpha_d fused ----------------
__global__ __launch_bounds__(256) void k_gemm_alpha(const float* __restrict__ xin, const float* __restrict__ W,
                                                    const float* __restrict__ a_src, const float* __restrict__ a_dst,
                                                    unsigned* __restrict__ hbf, float* __restrict__ as_out,
                                                    float* __restrict__ ad_out, int N, int iters) {
  __shared__ float Ws[HID * HID];
  __shared__ float xrow[4][HID];
  int t = threadIdx.x;
  for (int i = t * 4; i < HID * HID; i += 1024) *(float4*)&Ws[i] = *(const float4*)&W[i];
  int wave = t >> 6, lane = t & 63;
  int c0 = lane * 2, c1 = c0 + 1, head = lane >> 4;
  float as0 = a_src[c0], as1 = a_src[c1], ad0 = a_dst[c0], ad1 = a_dst[c1];
  __syncthreads();
  for (int it = 0; it < iters; ++it) {
    int r = (it * gridDim.x + blockIdx.x) * 4 + wave;
    if (r < N) {
      float2 xv = *(const float2*)&xin[(size_t)r * HID + c0];
      xrow[wave][c0] = xv.x;
      xrow[wave][c1] = xv.y;
    }
    __syncthreads();
    if (r < N) {
      float acc0 = 0.f, acc1 = 0.f;
#pragma unroll 8
      for (int k = 0; k < HID; ++k) {
        float xk = xrow[wave][k];
        float2 wv = *(const float2*)&Ws[k * HID + c0];
        acc0 = fmaf(xk, wv.x, acc0);
        acc1 = fmaf(xk, wv.y, acc1);
      }
      float ps = acc0 * as0 + acc1 * as1;
      float pd = acc0 * ad0 + acc1 * ad1;
#pragma unroll
      for (int msk = 1; msk < 16; msk <<= 1) {
        ps += __shfl_xor(ps, msk);
        pd += __shfl_xor(pd, msk);
      }
      if ((lane & 15) == 0) {
        as_out[r * 4 + head] = ps;
        ad_out[r * 4 + head] = pd;
      }
      hbf[(size_t)r * 64 + lane] = pack_bf2(acc0, acc1);
    }
    __syncthreads();
  }
}

// ---------------- per-dst softmax+agg+LN+ELU: one wave/dst, 4 edges/iter ----------------
// lane = g*16+q : g = edge group (4 edges in flight), q = channel block (8 ch), head = q>>2
__global__ __launch_bounds__(256) void k_gat_agg(const int* __restrict__ offs, const int* __restrict__ csr,
                                                 const float* __restrict__ as, const float* __restrict__ ad,
                                                 const uint4* __restrict__ hb, const float* __restrict__ bias,
                                                 const float* __restrict__ gam, const float* __restrict__ bet,
                                                 float* __restrict__ out, int N) {
  int wave = threadIdx.x >> 6, lane = threadIdx.x & 63;
  int dst = blockIdx.x * 4 + wave;
  if (dst >= N) return;
  int q = lane & 15, g = lane >> 4, head = q >> 2;
  float ad_h = ad[dst * 4 + head];
  float as_h = as[dst * 4 + head];
  float p_self = __expf(leaky(as_h + ad_h));
  float acc[8];
#pragma unroll
  for (int k = 0; k < 8; ++k) acc[k] = 0.f;
  float ssum = 0.f;
  int beg = offs[dst], end = offs[dst + 1];
  for (int base = beg; base < end; base += 64) {
    int idx = base + lane;
    int my = (idx < end) ? csr[idx] : 0;
    int cnt = min(64, end - base);
    for (int j = 0; j * 4 < cnt; ++j) {
      int sel = j * 4 + g;
      int s = __shfl(my, sel);
      bool v = sel < cnt;
      int ss = v ? s : 0;
      float asv = as[ss * 4 + head];
      float p = v ? __expf(leaky(asv + ad_h)) : 0.f;
      ssum += p;
      uint4 hr = hb[(size_t)ss * 16 + q];
#pragma unroll
      for (int k = 0; k < 4; ++k) {
        unsigned u = (&hr.x)[k];
        float f0 = __uint_as_float(u << 16);
        float f1 = __uint_as_float(u & 0xffff0000u);
        acc[2 * k]     = fmaf(p, f0, acc[2 * k]);
        acc[2 * k + 1] = fmaf(p, f1, acc[2 * k + 1]);
      }
    }
  }
  // combine the 4 edge groups (bits 4,5)
#pragma unroll
  for (int k = 0; k < 8; ++k) {
    acc[k] += __shfl_xor(acc[k], 16);
    acc[k] += __shfl_xor(acc[k], 32);
  }
  // per-head denom: sum over bits {0,1,4,5} counts each (edge,head) 4x -> *0.25
  float red = ssum;
  red += __shfl_xor(red, 1);
  red += __shfl_xor(red, 2);
  red += __shfl_xor(red, 16);
  red += __shfl_xor(red, 32);
  float denom = 0.25f * red + p_self;
  // self-loop contribution (after group-combine: all lanes add consistently)
  uint4 hd = hb[(size_t)dst * 16 + q];
#pragma unroll
  for (int k = 0; k < 4; ++k) {
    unsigned u = (&hd.x)[k];
    acc[2 * k]     = fmaf(p_self, __uint_as_float(u << 16), acc[2 * k]);
    acc[2 * k + 1] = fmaf(p_self, __uint_as_float(u & 0xffff0000u), acc[2 * k + 1]);
  }
  // normalize + bias
  int cb = q * 8;
  float inv = 1.f / denom;
  float val[8], part = 0.f;
#pragma unroll
  for (int k = 0; k < 8; ++k) {
    val[k] = acc[k] * inv + bias[cb + k];
    part += val[k];
  }
  // LayerNorm: reduce over q (bits 0..3)
  part += __shfl_xor(part, 1);
  part += __shfl_xor(part, 2);
  part += __shfl_xor(part, 4);
  part += __shfl_xor(part, 8);
  float mu = part * (1.f / HID);
  float vpart = 0.f;
#pragma unroll
  for (int k = 0; k < 8; ++k) {
    val[k] -= mu;
    vpart += val[k] * val[k];
  }
  vpart += __shfl_xor(vpart, 1);
  vpart += __shfl_xor(vpart, 2);
  vpart += __shfl_xor(vpart, 4);
  vpart += __shfl_xor(vpart, 8);
  float rstd = rsqrtf(vpart * (1.f / HID) + LN_EPS);
  float y[8];
#pragma unroll
  for (int k = 0; k < 8; ++k) {
    float t = val[k] * rstd * gam[cb + k] + bet[cb + k];
    y[k] = t > 0.f ? t : expm1f(t);
  }
  if (g == 0) {
    *(float4*)&out[(size_t)dst * HID + cb]     = make_float4(y[0], y[1], y[2], y[3]);
    *(float4*)&out[(size_t)dst * HID + cb + 4] = make_float4(y[4], y[5], y[6], y[7]);
  }
}

// ---------------- per-graph mean readout ----------------
__global__ __launch_bounds__(256) void k_graph_sum(const float* __restrict__ x, const int* __restrict__ bat,
                                                   float* __restrict__ gsum, float* __restrict__ gcnt, int N) {
  __shared__ float ls[NG * HID];
  __shared__ float lc[NG];
  for (int i = threadIdx.x; i < NG * HID; i += 256) ls[i] = 0.f;
  if (threadIdx.x < NG) lc[threadIdx.x] = 0.f;
  __syncthreads();
  int wave = threadIdx.x >> 6, lane = threadIdx.x & 63;
  for (int n = blockIdx.x * 4 + wave; n < N; n += gridDim.x * 4) {
    int b = bat[n];
    float2 v = *(const float2*)&x[(size_t)n * HID + lane * 2];
    atomicAdd(&ls[b * HID + lane * 2], v.x);
    atomicAdd(&ls[b * HID + lane * 2 + 1], v.y);
    if (lane == 0) atomicAdd(&lc[b], 1.f);
  }
  __syncthreads();
  for (int i = threadIdx.x; i < NG * HID; i += 256) atomicAdd(&gsum[i], ls[i]);
  if (threadIdx.x < NG) atomicAdd(&gcnt[threadIdx.x], lc[threadIdx.x]);
}

// fp32 output: [N, 256] = [x | g_global[batch]]
__global__ __launch_bounds__(256) void k_concat_out(const float* __restrict__ x, const int* __restrict__ bat,
                                                    const float* __restrict__ gsum, const float* __restrict__ gcnt,
                                                    float* __restrict__ out, int N) {
  int total = N * (HID / 4);
  for (int idx = blockIdx.x * blockDim.x + threadIdx.x; idx < total; idx += gridDim.x * blockDim.x) {
    int n = idx >> 5, q = idx & 31;
    int c = q * 4;
    float4 xv = *(const float4*)&x[(size_t)n * HID + c];
    int b = bat[n];
    float rin = 1.f / fmaxf(gcnt[b], 1.f);
    float4 gv = *(const float4*)&gsum[b * HID + c];
    *(float4*)&out[(size_t)n * 256 + c] = xv;
    *(float4*)&out[(size_t)n * 256 + 128 + c] =
        make_float4(gv.x * rin, gv.y * rin, gv.z * rin, gv.w * rin);
  }
}

extern "C" void kernel_launch(void* const* d_in, const int* in_sizes, int n_in,
                              void* d_out, int out_size, void* d_ws, size_t ws_size,
                              hipStream_t stream) {
  const float* x   = (const float*)d_in[0];
  const int*   ei  = (const int*)d_in[1];
  const int*   bat = (const int*)d_in[2];
  const float* W1  = (const float*)d_in[3];
  const float* as1 = (const float*)d_in[4];
  const float* ad1 = (const float*)d_in[5];
  const float* b1  = (const float*)d_in[6];
  const float* g1  = (const float*)d_in[7];
  const float* be1 = (const float*)d_in[8];
  const float* W2  = (const float*)d_in[9];
  const float* as2 = (const float*)d_in[10];
  const float* ad2 = (const float*)d_in[11];
  const float* b2  = (const float*)d_in[12];
  const float* g2  = (const float*)d_in[13];
  const float* be2 = (const float*)d_in[14];
  int N = in_sizes[0] / HID;
  int E = in_sizes[1] / 2;

  char* p = (char*)d_ws;
  auto alloc = [&](size_t bytes) {
    void* r = (void*)p;
    p += (bytes + 255) & ~(size_t)255;
    return r;
  };
  int*      deg  = (int*)alloc((size_t)N * 4);   // also fill cursor
  int*      offs = (int*)alloc((size_t)(N + 1) * 4);
  int       nsb  = (N + 1023) / 1024;
  int*      part = (int*)alloc((size_t)nsb * 4);
  int*      csr  = (int*)alloc((size_t)E * 4);
  unsigned* hbf  = (unsigned*)alloc((size_t)N * 64 * 4);  // bf16x2-packed h
  float*    asb  = (float*)alloc((size_t)N * 4 * 4);
  float*    adb  = (float*)alloc((size_t)N * 4 * 4);
  float*    xb   = (float*)alloc((size_t)N * HID * 4);
  float*    gsum = (float*)alloc((size_t)NG * HID * 4);
  float*    gcnt = (float*)alloc((size_t)NG * 4);

  hipMemsetAsync(deg, 0, (size_t)N * 4, stream);
  hipMemsetAsync(gsum, 0, (size_t)NG * HID * 4, stream);
  hipMemsetAsync(gcnt, 0, (size_t)NG * 4, stream);

  int egrid = (E + 255) / 256;
  if (egrid > 2048) egrid = 2048;
  k_edge_count<<<egrid, 256, 0, stream>>>(ei, E, deg);
  k_scan_a<<<nsb, 1024, 0, stream>>>(deg, offs, part, N);
  k_scan_b<<<1, 1024, 0, stream>>>(part, nsb);
  k_scan_c<<<(N + 255) / 256, 256, 0, stream>>>(offs, part, N);
  hipMemsetAsync(deg, 0, (size_t)N * 4, stream);  // cursor
  k_edge_fill<<<egrid, 256, 0, stream>>>(ei, E, offs, deg, csr);

  int ggrid = 512;
  int iters = (N + ggrid * 4 - 1) / (ggrid * 4);
  int agrid = (N + 3) / 4;

  k_gemm_alpha<<<ggrid, 256, 0, stream>>>(x, W1, as1, ad1, hbf, asb, adb, N, iters);
  k_gat_agg<<<agrid, 256, 0, stream>>>(offs, csr, asb, adb, (const uint4*)hbf, b1, g1, be1, xb, N);
  k_gemm_alpha<<<ggrid, 256, 0, stream>>>(xb, W2, as2, ad2, hbf, asb, adb, N, iters);
  k_gat_agg<<<agrid, 256, 0, stream>>>(offs, csr, asb, adb, (const uint4*)hbf, b2, g2, be2, xb, N);

  k_graph_sum<<<256, 256, 0, stream>>>(xb, bat, gsum, gcnt, N);
  int cgrid = (N * (HID / 4) + 255) / 256;
  if (cgrid > 4096) cgrid = 4096;
  k_concat_out<<<cgrid, 256, 0, stream>>>(xb, bat, gsum, gcnt, (float*)d_out, N);
}

// Round 7
// 651.695 us; speedup vs baseline: 7.8473x; 1.0052x over previous
//
#include <hip/hip_runtime.h>
#include <hip/hip_bf16.h>

#define HID 128
#define NEG 0.2f
#define LN_EPS 1e-5f
#define NG 16

static __device__ __forceinline__ float leaky(float x) { return x > 0.f ? x : NEG * x; }

static __device__ __forceinline__ unsigned pack_bf2(float a, float b) {
  __hip_bfloat16 ha = __float2bfloat16(a), hb = __float2bfloat16(b);
  unsigned ua = *reinterpret_cast<unsigned short*>(&ha);
  unsigned ub = *reinterpret_cast<unsigned short*>(&hb);
  return ua | (ub << 16);
}

// ---------------- CSR build ----------------
__global__ __launch_bounds__(256) void k_edge_count(const int* __restrict__ ei, int E,
                                                    int* __restrict__ deg) {
  for (int e = blockIdx.x * blockDim.x + threadIdx.x; e < E; e += gridDim.x * blockDim.x)
    atomicAdd(&deg[ei[E + e]], 1);
}

__global__ __launch_bounds__(1024) void k_scan_a(const int* __restrict__ deg, int* __restrict__ offs,
                                                 int* __restrict__ part, int N) {
  __shared__ int s[1024];
  int i = blockIdx.x * 1024 + threadIdx.x;
  int v = (i < N) ? deg[i] : 0;
  s[threadIdx.x] = v;
  __syncthreads();
  for (int d = 1; d < 1024; d <<= 1) {
    int t = (threadIdx.x >= d) ? s[threadIdx.x - d] : 0;
    __syncthreads();
    s[threadIdx.x] += t;
    __syncthreads();
  }
  if (i < N) offs[i + 1] = s[threadIdx.x];
  if (threadIdx.x == 1023) part[blockIdx.x] = s[1023];
}

__global__ __launch_bounds__(1024) void k_scan_b(int* __restrict__ part, int nb) {
  __shared__ int s[1024];
  int v = (threadIdx.x < nb) ? part[threadIdx.x] : 0;
  s[threadIdx.x] = v;
  __syncthreads();
  for (int d = 1; d < 1024; d <<= 1) {
    int t = (threadIdx.x >= d) ? s[threadIdx.x - d] : 0;
    __syncthreads();
    s[threadIdx.x] += t;
    __syncthreads();
  }
  if (threadIdx.x < nb) part[threadIdx.x] = (threadIdx.x == 0) ? 0 : s[threadIdx.x - 1];
}

__global__ __launch_bounds__(256) void k_scan_c(int* __restrict__ offs, const int* __restrict__ part, int N) {
  int i = blockIdx.x * blockDim.x + threadIdx.x;
  if (i < N) offs[i + 1] += part[i >> 10];
  if (i == 0) offs[0] = 0;
}

__global__ __launch_bounds__(256) void k_edge_fill(const int* __restrict__ ei, int E,
                                                   const int* __restrict__ offs,
                                                   int* __restrict__ cursor, int* __restrict__ csr) {
  for (int e = blockIdx.x * blockDim.x + threadIdx.x; e < E; e += gridDim.x * blockDim.x) {
    int d = ei[E + e];
    int slot = atomicAdd(&cursor[d], 1);
    csr[offs[d] + slot] = ei[e];
  }
}

// ---------------- Wa[k][o] = sum_d W[k][h*32+d]*a[h][d]  (o<4: a_src, o>=4: a_dst) ----------------
__global__ __launch_bounds__(1024) void k_wprep(const float* __restrict__ W, const float* __restrict__ a_s,
                                                const float* __restrict__ a_d, float* __restrict__ wa) {
  int t = threadIdx.x;  // 1024 = 128 k x 8 o
  int k = t >> 3, o = t & 7;
  int hh = o & 3;
  const float* av = (o < 4) ? a_s : a_d;
  float acc = 0.f;
#pragma unroll
  for (int d = 0; d < 32; ++d) acc = fmaf(W[k * HID + hh * 32 + d], av[hh * 32 + d], acc);
  wa[k * 8 + o] = acc;
}

// ---------------- tiled GEMM: h(bf16-packed) = x @ W ; as/ad = x @ Wa ----------------
// 512 threads: wave rq = t>>6 owns rows rq*8..rq*8+7 of the 64-row tile; pr = t&63 -> cols 2pr,2pr+1
__global__ __launch_bounds__(512) void k_gemm(const float* __restrict__ xin, const float* __restrict__ W,
                                              const float* __restrict__ wa, unsigned* __restrict__ hbf,
                                              float* __restrict__ as_out, float* __restrict__ ad_out,
                                              int N, int ntiles) {
  __shared__ float Ws[HID * HID];     // 64 KB
  __shared__ float xs[64][HID];       // 32 KB
  __shared__ float Wa[HID * 8];       // 4 KB
  int t = threadIdx.x;
  for (int i = t * 4; i < HID * HID; i += 2048) *(float4*)&Ws[i] = *(const float4*)&W[i];
  if (t < 256) *(float4*)&Wa[t * 4] = *(const float4*)&wa[t * 4];
  int rq = t >> 6, pr = t & 63;
  int c2 = pr * 2;
  for (int tile = blockIdx.x; tile < ntiles; tile += gridDim.x) {
    int r0 = tile * 64;
    __syncthreads();
    // stage 64 rows of x
#pragma unroll
    for (int i = 0; i < 4; ++i) {
      int idx = i * 512 + t;
      int r = idx >> 5, q = idx & 31;
      float4 v = make_float4(0.f, 0.f, 0.f, 0.f);
      if (r0 + r < N) v = *(const float4*)&xin[(size_t)(r0 + r) * HID + q * 4];
      *(float4*)&xs[r][q * 4] = v;
    }
    __syncthreads();
    // main: 8 rows x 2 cols per thread
    float acc[8][2];
#pragma unroll
    for (int r = 0; r < 8; ++r) { acc[r][0] = 0.f; acc[r][1] = 0.f; }
    for (int k0 = 0; k0 < HID; k0 += 4) {
      float2 w0 = *(const float2*)&Ws[(k0 + 0) * HID + c2];
      float2 w1 = *(const float2*)&Ws[(k0 + 1) * HID + c2];
      float2 w2 = *(const float2*)&Ws[(k0 + 2) * HID + c2];
      float2 w3 = *(const float2*)&Ws[(k0 + 3) * HID + c2];
#pragma unroll
      for (int r = 0; r < 8; ++r) {
        float4 xv = *(const float4*)&xs[rq * 8 + r][k0];
        acc[r][0] = fmaf(xv.x, w0.x, acc[r][0]);
        acc[r][1] = fmaf(xv.x, w0.y, acc[r][1]);
        acc[r][0] = fmaf(xv.y, w1.x, acc[r][0]);
        acc[r][1] = fmaf(xv.y, w1.y, acc[r][1]);
        acc[r][0] = fmaf(xv.z, w2.x, acc[r][0]);
        acc[r][1] = fmaf(xv.z, w2.y, acc[r][1]);
        acc[r][0] = fmaf(xv.w, w3.x, acc[r][0]);
        acc[r][1] = fmaf(xv.w, w3.y, acc[r][1]);
      }
    }
#pragma unroll
    for (int r = 0; r < 8; ++r) {
      int row = r0 + rq * 8 + r;
      if (row < N) hbf[(size_t)row * 64 + pr] = pack_bf2(acc[r][0], acc[r][1]);
    }
    // alpha phase: 64 rows x 8 outputs, thread = (row, o)
    {
      int r = t >> 3, o = t & 7;
      int row = r0 + r;
      if (row < N) {
        float s = 0.f;
        for (int k0 = 0; k0 < HID; k0 += 4) {
          float4 xv = *(const float4*)&xs[r][k0];
          s = fmaf(xv.x, Wa[(k0 + 0) * 8 + o], s);
          s = fmaf(xv.y, Wa[(k0 + 1) * 8 + o], s);
          s = fmaf(xv.z, Wa[(k0 + 2) * 8 + o], s);
          s = fmaf(xv.w, Wa[(k0 + 3) * 8 + o], s);
        }
        if (o < 4) as_out[row * 4 + o] = s;
        else       ad_out[row * 4 + (o - 4)] = s;
      }
    }
  }
}

// ---------------- per-dst softmax+agg+LN+ELU: wave/dst, 8 edges in flight ----------------
// lane = g*8+q : g = edge slot (8 edges), q = channel block (16 ch), head = q>>1
__global__ __launch_bounds__(256) void k_gat_agg(const int* __restrict__ offs, const int* __restrict__ csr,
                                                 const float* __restrict__ as, const float* __restrict__ ad,
                                                 const uint4* __restrict__ hb, const float* __restrict__ bias,
                                                 const float* __restrict__ gam, const float* __restrict__ bet,
                                                 float* __restrict__ out, float* __restrict__ xout, int N) {
  int wave = threadIdx.x >> 6, lane = threadIdx.x & 63;
  int dst = blockIdx.x * 4 + wave;
  if (dst >= N) return;
  int q = lane & 7, g = lane >> 3, head = q >> 1;
  float ad_h = ad[dst * 4 + head];
  float p_self = __expf(leaky(as[dst * 4 + head] + ad_h));
  float acc[16];
#pragma unroll
  for (int k = 0; k < 16; ++k) acc[k] = 0.f;
  float ssum = 0.f;
  int beg = offs[dst], end = offs[dst + 1];
  for (int base = beg; base < end; base += 64) {
    int idx = base + lane;
    int my = (idx < end) ? csr[idx] : 0;
    int cnt = min(64, end - base);
    for (int j = 0; j * 8 < cnt; ++j) {
      int sel = j * 8 + g;
      int s = __shfl(my, sel);
      bool v = sel < cnt;
      int ss = v ? s : 0;
      float p = v ? __expf(leaky(as[ss * 4 + head] + ad_h)) : 0.f;
      ssum += p;
      uint4 h0 = hb[(size_t)ss * 16 + q * 2];
      uint4 h1 = hb[(size_t)ss * 16 + q * 2 + 1];
#pragma unroll
      for (int k = 0; k < 4; ++k) {
        unsigned u = (&h0.x)[k];
        acc[2 * k]     = fmaf(p, __uint_as_float(u << 16), acc[2 * k]);
        acc[2 * k + 1] = fmaf(p, __uint_as_float(u & 0xffff0000u), acc[2 * k + 1]);
        unsigned u2 = (&h1.x)[k];
        acc[8 + 2 * k]     = fmaf(p, __uint_as_float(u2 << 16), acc[8 + 2 * k]);
        acc[8 + 2 * k + 1] = fmaf(p, __uint_as_float(u2 & 0xffff0000u), acc[8 + 2 * k + 1]);
      }
    }
  }
  // combine the 8 edge groups (bits 3,4,5)
#pragma unroll
  for (int k = 0; k < 16; ++k) {
    acc[k] += __shfl_xor(acc[k], 8);
    acc[k] += __shfl_xor(acc[k], 16);
    acc[k] += __shfl_xor(acc[k], 32);
  }
  // denom: sum over bits {0,3,4,5}; each (edge,head) counted 2x -> *0.5
  float red = ssum;
  red += __shfl_xor(red, 1);
  red += __shfl_xor(red, 8);
  red += __shfl_xor(red, 16);
  red += __shfl_xor(red, 32);
  float denom = 0.5f * red + p_self;
  // self-loop
  uint4 h0 = hb[(size_t)dst * 16 + q * 2];
  uint4 h1 = hb[(size_t)dst * 16 + q * 2 + 1];
#pragma unroll
  for (int k = 0; k < 4; ++k) {
    unsigned u = (&h0.x)[k];
    acc[2 * k]     = fmaf(p_self, __uint_as_float(u << 16), acc[2 * k]);
    acc[2 * k + 1] = fmaf(p_self, __uint_as_float(u & 0xffff0000u), acc[2 * k + 1]);
    unsigned u2 = (&h1.x)[k];
    acc[8 + 2 * k]     = fmaf(p_self, __uint_as_float(u2 << 16), acc[8 + 2 * k]);
    acc[8 + 2 * k + 1] = fmaf(p_self, __uint_as_float(u2 & 0xffff0000u), acc[8 + 2 * k + 1]);
  }
  // normalize + bias
  int cb = q * 16;
  float inv = 1.f / denom;
  float val[16], part = 0.f;
#pragma unroll
  for (int k = 0; k < 16; ++k) {
    val[k] = acc[k] * inv + bias[cb + k];
    part += val[k];
  }
  // LayerNorm: reduce over q (bits 0,1,2)
  part += __shfl_xor(part, 1);
  part += __shfl_xor(part, 2);
  part += __shfl_xor(part, 4);
  float mu = part * (1.f / HID);
  float vpart = 0.f;
#pragma unroll
  for (int k = 0; k < 16; ++k) {
    val[k] -= mu;
    vpart += val[k] * val[k];
  }
  vpart += __shfl_xor(vpart, 1);
  vpart += __shfl_xor(vpart, 2);
  vpart += __shfl_xor(vpart, 4);
  float rstd = rsqrtf(vpart * (1.f / HID) + LN_EPS);
  float y[16];
#pragma unroll
  for (int k = 0; k < 16; ++k) {
    float tv = val[k] * rstd * gam[cb + k] + bet[cb + k];
    y[k] = tv > 0.f ? tv : expm1f(tv);
  }
  if (g == 0) {
#pragma unroll
    for (int k = 0; k < 4; ++k)
      *(float4*)&out[(size_t)dst * HID + cb + k * 4] = make_float4(y[4 * k], y[4 * k + 1], y[4 * k + 2], y[4 * k + 3]);
    if (xout) {
#pragma unroll
      for (int k = 0; k < 4; ++k)
        *(float4*)&xout[(size_t)dst * 256 + cb + k * 4] = make_float4(y[4 * k], y[4 * k + 1], y[4 * k + 2], y[4 * k + 3]);
    }
  }
}

// ---------------- per-graph mean readout ----------------
__global__ __launch_bounds__(256) void k_graph_sum(const float* __restrict__ x, const int* __restrict__ bat,
                                                   float* __restrict__ gsum, float* __restrict__ gcnt, int N) {
  __shared__ float ls[NG * HID];
  __shared__ float lc[NG];
  for (int i = threadIdx.x; i < NG * HID; i += 256) ls[i] = 0.f;
  if (threadIdx.x < NG) lc[threadIdx.x] = 0.f;
  __syncthreads();
  int wave = threadIdx.x >> 6, lane = threadIdx.x & 63;
  for (int n = blockIdx.x * 4 + wave; n < N; n += gridDim.x * 4) {
    int b = bat[n];
    float2 v = *(const float2*)&x[(size_t)n * HID + lane * 2];
    atomicAdd(&ls[b * HID + lane * 2], v.x);
    atomicAdd(&ls[b * HID + lane * 2 + 1], v.y);
    if (lane == 0) atomicAdd(&lc[b], 1.f);
  }
  __syncthreads();
  for (int i = threadIdx.x; i < NG * HID; i += 256) atomicAdd(&gsum[i], ls[i]);
  if (threadIdx.x < NG) atomicAdd(&gcnt[threadIdx.x], lc[threadIdx.x]);
}

// g-half of output only
__global__ __launch_bounds__(256) void k_gout(const int* __restrict__ bat, const float* __restrict__ gsum,
                                              const float* __restrict__ gcnt, float* __restrict__ out, int N) {
  int total = N * 32;
  for (int idx = blockIdx.x * blockDim.x + threadIdx.x; idx < total; idx += gridDim.x * blockDim.x) {
    int n = idx >> 5, qq = idx & 31;
    int b = bat[n];
    float rin = 1.f / fmaxf(gcnt[b], 1.f);
    float4 gv = *(const float4*)&gsum[b * HID + qq * 4];
    *(float4*)&out[(size_t)n * 256 + 128 + qq * 4] =
        make_float4(gv.x * rin, gv.y * rin, gv.z * rin, gv.w * rin);
  }
}

extern "C" void kernel_launch(void* const* d_in, const int* in_sizes, int n_in,
                              void* d_out, int out_size, void* d_ws, size_t ws_size,
                              hipStream_t stream) {
  const float* x   = (const float*)d_in[0];
  const int*   ei  = (const int*)d_in[1];
  const int*   bat = (const int*)d_in[2];
  const float* W1  = (const float*)d_in[3];
  const float* as1 = (const float*)d_in[4];
  const float* ad1 = (const float*)d_in[5];
  const float* b1  = (const float*)d_in[6];
  const float* g1  = (const float*)d_in[7];
  const float* be1 = (const float*)d_in[8];
  const float* W2  = (const float*)d_in[9];
  const float* as2 = (const float*)d_in[10];
  const float* ad2 = (const float*)d_in[11];
  const float* b2  = (const float*)d_in[12];
  const float* g2  = (const float*)d_in[13];
  const float* be2 = (const float*)d_in[14];
  int N = in_sizes[0] / HID;
  int E = in_sizes[1] / 2;

  char* p = (char*)d_ws;
  auto alloc = [&](size_t bytes) {
    void* r = (void*)p;
    p += (bytes + 255) & ~(size_t)255;
    return r;
  };
  int*      deg  = (int*)alloc((size_t)N * 4);   // also fill cursor
  int*      offs = (int*)alloc((size_t)(N + 1) * 4);
  int       nsb  = (N + 1023) / 1024;
  int*      part = (int*)alloc((size_t)nsb * 4);
  int*      csr  = (int*)alloc((size_t)E * 4);
  unsigned* hbf  = (unsigned*)alloc((size_t)N * 64 * 4);  // bf16x2-packed h
  float*    asb  = (float*)alloc((size_t)N * 4 * 4);
  float*    adb  = (float*)alloc((size_t)N * 4 * 4);
  float*    xb   = (float*)alloc((size_t)N * HID * 4);
  float*    wa   = (float*)alloc((size_t)HID * 8 * 4);
  float*    gsum = (float*)alloc((size_t)NG * HID * 4);
  float*    gcnt = (float*)alloc((size_t)NG * 4);

  hipMemsetAsync(deg, 0, (size_t)N * 4, stream);
  hipMemsetAsync(gsum, 0, (size_t)NG * HID * 4, stream);
  hipMemsetAsync(gcnt, 0, (size_t)NG * 4, stream);

  int egrid = (E + 255) / 256;
  if (egrid > 2048) egrid = 2048;
  k_edge_count<<<egrid, 256, 0, stream>>>(ei, E, deg);
  k_scan_a<<<nsb, 1024, 0, stream>>>(deg, offs, part, N);
  k_scan_b<<<1, 1024, 0, stream>>>(part, nsb);
  k_scan_c<<<(N + 255) / 256, 256, 0, stream>>>(offs, part, N);
  hipMemsetAsync(deg, 0, (size_t)N * 4, stream);  // cursor
  k_edge_fill<<<egrid, 256, 0, stream>>>(ei, E, offs, deg, csr);

  int ntiles = (N + 63) / 64;
  int ggrid = ntiles < 256 ? ntiles : 256;
  int agrid = (N + 3) / 4;

  k_wprep<<<1, 1024, 0, stream>>>(W1, as1, ad1, wa);
  k_gemm<<<ggrid, 512, 0, stream>>>(x, W1, wa, hbf, asb, adb, N, ntiles);
  k_gat_agg<<<agrid, 256, 0, stream>>>(offs, csr, asb, adb, (const uint4*)hbf, b1, g1, be1, xb, nullptr, N);
  k_wprep<<<1, 1024, 0, stream>>>(W2, as2, ad2, wa);
  k_gemm<<<ggrid, 512, 0, stream>>>(xb, W2, wa, hbf, asb, adb, N, ntiles);
  k_gat_agg<<<agrid, 256, 0, stream>>>(offs, csr, asb, adb, (const uint4*)hbf, b2, g2, be2, xb, (float*)d_out, N);

  k_graph_sum<<<256, 256, 0, stream>>>(xb, bat, gsum, gcnt, N);
  int ogrid = (N * 32 + 255) / 256;
  if (ogrid > 4096) ogrid = 4096;
  k_gout<<<ogrid, 256, 0, stream>>>(bat, gsum, gcnt, (float*)d_out, N);
}

// Round 8
// 555.183 us; speedup vs baseline: 9.2114x; 1.1738x over previous
//
#include <hip/hip_runtime.h>
#include <hip/hip_bf16.h>

#define HID 128
#define NEG 0.2f
#define LN_EPS 1e-5f
#define NG 16

static __device__ __forceinline__ float leaky(float x) { return x > 0.f ? x : NEG * x; }

static __device__ __forceinline__ unsigned pack_bf2(float a, float b) {
  __hip_bfloat16 ha = __float2bfloat16(a), hb = __float2bfloat16(b);
  unsigned ua = *reinterpret_cast<unsigned short*>(&ha);
  unsigned ub = *reinterpret_cast<unsigned short*>(&hb);
  return ua | (ub << 16);
}

// ---------------- CSR build ----------------
__global__ __launch_bounds__(256) void k_edge_count(const int* __restrict__ ei, int E,
                                                    int* __restrict__ deg) {
  for (int e = blockIdx.x * blockDim.x + threadIdx.x; e < E; e += gridDim.x * blockDim.x)
    atomicAdd(&deg[ei[E + e]], 1);
}

__global__ __launch_bounds__(1024) void k_scan_a(const int* __restrict__ deg, int* __restrict__ offs,
                                                 int* __restrict__ part, int N) {
  __shared__ int s[1024];
  int i = blockIdx.x * 1024 + threadIdx.x;
  int v = (i < N) ? deg[i] : 0;
  s[threadIdx.x] = v;
  __syncthreads();
  for (int d = 1; d < 1024; d <<= 1) {
    int t = (threadIdx.x >= d) ? s[threadIdx.x - d] : 0;
    __syncthreads();
    s[threadIdx.x] += t;
    __syncthreads();
  }
  if (i < N) offs[i + 1] = s[threadIdx.x];
  if (threadIdx.x == 1023) part[blockIdx.x] = s[1023];
}

__global__ __launch_bounds__(1024) void k_scan_b(int* __restrict__ part, int nb) {
  __shared__ int s[1024];
  int v = (threadIdx.x < nb) ? part[threadIdx.x] : 0;
  s[threadIdx.x] = v;
  __syncthreads();
  for (int d = 1; d < 1024; d <<= 1) {
    int t = (threadIdx.x >= d) ? s[threadIdx.x - d] : 0;
    __syncthreads();
    s[threadIdx.x] += t;
    __syncthreads();
  }
  if (threadIdx.x < nb) part[threadIdx.x] = (threadIdx.x == 0) ? 0 : s[threadIdx.x - 1];
}

__global__ __launch_bounds__(256) void k_scan_c(int* __restrict__ offs, const int* __restrict__ part, int N) {
  int i = blockIdx.x * blockDim.x + threadIdx.x;
  if (i < N) offs[i + 1] += part[i >> 10];
  if (i == 0) offs[0] = 0;
}

__global__ __launch_bounds__(256) void k_edge_fill(const int* __restrict__ ei, int E,
                                                   const int* __restrict__ offs,
                                                   int* __restrict__ cursor, int* __restrict__ csr) {
  for (int e = blockIdx.x * blockDim.x + threadIdx.x; e < E; e += gridDim.x * blockDim.x) {
    int d = ei[E + e];
    int slot = atomicAdd(&cursor[d], 1);
    csr[offs[d] + slot] = ei[e];
  }
}

// ---------------- tiled GEMM: h(bf16) = x @ W ; as/ad reduced in-wave ----------------
// 512 thr = 8 waves; wave rq owns rows rq*4..rq*4+3 of a 32-row tile; lane pr -> cols 2pr,2pr+1
__global__ __launch_bounds__(512) void k_gemm(const float* __restrict__ xin, const float* __restrict__ W,
                                              const float* __restrict__ a_s, const float* __restrict__ a_d,
                                              unsigned* __restrict__ hbf, float* __restrict__ as_out,
                                              float* __restrict__ ad_out, int N, int ntiles) {
  __shared__ float Ws[HID * HID];   // 64 KB
  __shared__ float xs[32][HID];     // 16 KB  -> 80 KB total, 2 blocks/CU
  int t = threadIdx.x;
  for (int i = t * 4; i < HID * HID; i += 2048) *(float4*)&Ws[i] = *(const float4*)&W[i];
  int rq = t >> 6, pr = t & 63;
  int c2 = pr * 2;
  float a_s0 = a_s[c2], a_s1 = a_s[c2 + 1], a_d0 = a_d[c2], a_d1 = a_d[c2 + 1];
  for (int tile = blockIdx.x; tile < ntiles; tile += gridDim.x) {
    int r0 = tile * 32;
    __syncthreads();
    // stage 32 rows (1024 float4, 2 per thread)
#pragma unroll
    for (int i = 0; i < 2; ++i) {
      int idx = i * 512 + t;
      int r = idx >> 5, q = idx & 31;
      float4 v = make_float4(0.f, 0.f, 0.f, 0.f);
      if (r0 + r < N) v = *(const float4*)&xin[(size_t)(r0 + r) * HID + q * 4];
      *(float4*)&xs[r][q * 4] = v;
    }
    __syncthreads();
    float acc[4][2];
#pragma unroll
    for (int r = 0; r < 4; ++r) { acc[r][0] = 0.f; acc[r][1] = 0.f; }
    for (int k0 = 0; k0 < HID; k0 += 4) {
      float2 w0 = *(const float2*)&Ws[(k0 + 0) * HID + c2];
      float2 w1 = *(const float2*)&Ws[(k0 + 1) * HID + c2];
      float2 w2 = *(const float2*)&Ws[(k0 + 2) * HID + c2];
      float2 w3 = *(const float2*)&Ws[(k0 + 3) * HID + c2];
#pragma unroll
      for (int r = 0; r < 4; ++r) {
        float4 xv = *(const float4*)&xs[rq * 4 + r][k0];
        acc[r][0] = fmaf(xv.x, w0.x, acc[r][0]);
        acc[r][1] = fmaf(xv.x, w0.y, acc[r][1]);
        acc[r][0] = fmaf(xv.y, w1.x, acc[r][0]);
        acc[r][1] = fmaf(xv.y, w1.y, acc[r][1]);
        acc[r][0] = fmaf(xv.z, w2.x, acc[r][0]);
        acc[r][1] = fmaf(xv.z, w2.y, acc[r][1]);
        acc[r][0] = fmaf(xv.w, w3.x, acc[r][0]);
        acc[r][1] = fmaf(xv.w, w3.y, acc[r][1]);
      }
    }
#pragma unroll
    for (int r = 0; r < 4; ++r) {
      int row = r0 + rq * 4 + r;
      float ps = acc[r][0] * a_s0 + acc[r][1] * a_s1;
      float pd = acc[r][0] * a_d0 + acc[r][1] * a_d1;
#pragma unroll
      for (int msk = 1; msk < 16; msk <<= 1) {
        ps += __shfl_xor(ps, msk);
        pd += __shfl_xor(pd, msk);
      }
      if (row < N) {
        hbf[(size_t)row * 64 + pr] = pack_bf2(acc[r][0], acc[r][1]);
        if ((pr & 15) == 0) {
          as_out[row * 4 + (pr >> 4)] = ps;
          ad_out[row * 4 + (pr >> 4)] = pd;
        }
      }
    }
  }
}

// ---------------- per-dst softmax+agg+LN+ELU: wave/dst, 4 edges in flight, 2-deep pipeline ----------------
// lane = g*16+q : g = edge slot (4), q = channel block (8 ch), head = q>>2
__global__ __launch_bounds__(256) void k_gat_agg(const int* __restrict__ offs, const int* __restrict__ csr,
                                                 const float* __restrict__ as, const float* __restrict__ ad,
                                                 const uint4* __restrict__ hb, const float* __restrict__ bias,
                                                 const float* __restrict__ gam, const float* __restrict__ bet,
                                                 float* __restrict__ out, int ostride, int N) {
  int wave = threadIdx.x >> 6, lane = threadIdx.x & 63;
  int dst = blockIdx.x * 4 + wave;
  if (dst >= N) return;
  int q = lane & 15, g = lane >> 4, head = q >> 2;
  float ad_h = ad[dst * 4 + head];
  float p_self = __expf(leaky(as[dst * 4 + head] + ad_h));
  float acc[8];
#pragma unroll
  for (int k = 0; k < 8; ++k) acc[k] = 0.f;
  float ssum = 0.f;
  int beg = offs[dst], end = offs[dst + 1];
  for (int base = beg; base < end; base += 64) {
    int idx = base + lane;
    int my = (idx < end) ? csr[idx] : 0;
    int cnt = min(64, end - base);
    int njj = (cnt + 3) >> 2;
    // prefetch j=0
    int s0 = __shfl(my, g);
    bool v0 = g < cnt;
    int ss0 = v0 ? s0 : 0;
    float asv0 = as[ss0 * 4 + head];
    uint4 h0 = hb[(size_t)ss0 * 16 + q];
    for (int j = 0; j < njj; ++j) {
      // issue next iteration's loads (branchless; clamped to row 0 when invalid)
      int sel1 = (j + 1) * 4 + g;
      int s1 = __shfl(my, sel1 & 63);
      bool v1 = sel1 < cnt;
      int ss1 = v1 ? s1 : 0;
      float asv1 = as[ss1 * 4 + head];
      uint4 h1 = hb[(size_t)ss1 * 16 + q];
      // consume current
      float p = v0 ? __expf(leaky(asv0 + ad_h)) : 0.f;
      ssum += p;
#pragma unroll
      for (int k = 0; k < 4; ++k) {
        unsigned u = (&h0.x)[k];
        acc[2 * k]     = fmaf(p, __uint_as_float(u << 16), acc[2 * k]);
        acc[2 * k + 1] = fmaf(p, __uint_as_float(u & 0xffff0000u), acc[2 * k + 1]);
      }
      v0 = v1; asv0 = asv1; h0 = h1;
    }
  }
  // combine the 4 edge groups (bits 4,5)
#pragma unroll
  for (int k = 0; k < 8; ++k) {
    acc[k] += __shfl_xor(acc[k], 16);
    acc[k] += __shfl_xor(acc[k], 32);
  }
  // denom: sum over bits {0,1,4,5}; each (edge,head) counted 4x -> *0.25
  float red = ssum;
  red += __shfl_xor(red, 1);
  red += __shfl_xor(red, 2);
  red += __shfl_xor(red, 16);
  red += __shfl_xor(red, 32);
  float denom = 0.25f * red + p_self;
  // self-loop
  uint4 hd = hb[(size_t)dst * 16 + q];
#pragma unroll
  for (int k = 0; k < 4; ++k) {
    unsigned u = (&hd.x)[k];
    acc[2 * k]     = fmaf(p_self, __uint_as_float(u << 16), acc[2 * k]);
    acc[2 * k + 1] = fmaf(p_self, __uint_as_float(u & 0xffff0000u), acc[2 * k + 1]);
  }
  // normalize + bias
  int cb = q * 8;
  float inv = 1.f / denom;
  float val[8], part = 0.f;
#pragma unroll
  for (int k = 0; k < 8; ++k) {
    val[k] = acc[k] * inv + bias[cb + k];
    part += val[k];
  }
  // LayerNorm: reduce over q (bits 0..3)
  part += __shfl_xor(part, 1);
  part += __shfl_xor(part, 2);
  part += __shfl_xor(part, 4);
  part += __shfl_xor(part, 8);
  float mu = part * (1.f / HID);
  float vpart = 0.f;
#pragma unroll
  for (int k = 0; k < 8; ++k) {
    val[k] -= mu;
    vpart += val[k] * val[k];
  }
  vpart += __shfl_xor(vpart, 1);
  vpart += __shfl_xor(vpart, 2);
  vpart += __shfl_xor(vpart, 4);
  vpart += __shfl_xor(vpart, 8);
  float rstd = rsqrtf(vpart * (1.f / HID) + LN_EPS);
  float y[8];
#pragma unroll
  for (int k = 0; k < 8; ++k) {
    float tv = val[k] * rstd * gam[cb + k] + bet[cb + k];
    y[k] = tv > 0.f ? tv : expm1f(tv);
  }
  if (g == 0) {
    *(float4*)&out[(size_t)dst * ostride + cb]     = make_float4(y[0], y[1], y[2], y[3]);
    *(float4*)&out[(size_t)dst * ostride + cb + 4] = make_float4(y[4], y[5], y[6], y[7]);
  }
}

// ---------------- per-graph mean readout (reads strided x) ----------------
__global__ __launch_bounds__(256) void k_graph_sum(const float* __restrict__ x, int xstride,
                                                   const int* __restrict__ bat,
                                                   float* __restrict__ gsum, float* __restrict__ gcnt, int N) {
  __shared__ float ls[NG * HID];
  __shared__ float lc[NG];
  for (int i = threadIdx.x; i < NG * HID; i += 256) ls[i] = 0.f;
  if (threadIdx.x < NG) lc[threadIdx.x] = 0.f;
  __syncthreads();
  int wave = threadIdx.x >> 6, lane = threadIdx.x & 63;
  for (int n = blockIdx.x * 4 + wave; n < N; n += gridDim.x * 4) {
    int b = bat[n];
    float2 v = *(const float2*)&x[(size_t)n * xstride + lane * 2];
    atomicAdd(&ls[b * HID + lane * 2], v.x);
    atomicAdd(&ls[b * HID + lane * 2 + 1], v.y);
    if (lane == 0) atomicAdd(&lc[b], 1.f);
  }
  __syncthreads();
  for (int i = threadIdx.x; i < NG * HID; i += 256) atomicAdd(&gsum[i], ls[i]);
  if (threadIdx.x < NG) atomicAdd(&gcnt[threadIdx.x], lc[threadIdx.x]);
}

// g-half of output
__global__ __launch_bounds__(256) void k_gout(const int* __restrict__ bat, const float* __restrict__ gsum,
                                              const float* __restrict__ gcnt, float* __restrict__ out, int N) {
  int total = N * 32;
  for (int idx = blockIdx.x * blockDim.x + threadIdx.x; idx < total; idx += gridDim.x * blockDim.x) {
    int n = idx >> 5, qq = idx & 31;
    int b = bat[n];
    float rin = 1.f / fmaxf(gcnt[b], 1.f);
    float4 gv = *(const float4*)&gsum[b * HID + qq * 4];
    *(float4*)&out[(size_t)n * 256 + 128 + qq * 4] =
        make_float4(gv.x * rin, gv.y * rin, gv.z * rin, gv.w * rin);
  }
}

extern "C" void kernel_launch(void* const* d_in, const int* in_sizes, int n_in,
                              void* d_out, int out_size, void* d_ws, size_t ws_size,
                              hipStream_t stream) {
  const float* x   = (const float*)d_in[0];
  const int*   ei  = (const int*)d_in[1];
  const int*   bat = (const int*)d_in[2];
  const float* W1  = (const float*)d_in[3];
  const float* as1 = (const float*)d_in[4];
  const float* ad1 = (const float*)d_in[5];
  const float* b1  = (const float*)d_in[6];
  const float* g1  = (const float*)d_in[7];
  const float* be1 = (const float*)d_in[8];
  const float* W2  = (const float*)d_in[9];
  const float* as2 = (const float*)d_in[10];
  const float* ad2 = (const float*)d_in[11];
  const float* b2  = (const float*)d_in[12];
  const float* g2  = (const float*)d_in[13];
  const float* be2 = (const float*)d_in[14];
  int N = in_sizes[0] / HID;
  int E = in_sizes[1] / 2;

  char* p = (char*)d_ws;
  auto alloc = [&](size_t bytes) {
    void* r = (void*)p;
    p += (bytes + 255) & ~(size_t)255;
    return r;
  };
  int*      deg  = (int*)alloc((size_t)N * 4);   // also fill cursor
  int*      offs = (int*)alloc((size_t)(N + 1) * 4);
  int       nsb  = (N + 1023) / 1024;
  int*      part = (int*)alloc((size_t)nsb * 4);
  int*      csr  = (int*)alloc((size_t)E * 4);
  unsigned* hbf  = (unsigned*)alloc((size_t)N * 64 * 4);  // bf16x2-packed h
  float*    asb  = (float*)alloc((size_t)N * 4 * 4);
  float*    adb  = (float*)alloc((size_t)N * 4 * 4);
  float*    xb   = (float*)alloc((size_t)N * HID * 4);
  float*    gsum = (float*)alloc((size_t)NG * HID * 4);
  float*    gcnt = (float*)alloc((size_t)NG * 4);

  hipMemsetAsync(deg, 0, (size_t)N * 4, stream);
  hipMemsetAsync(gsum, 0, (size_t)NG * HID * 4, stream);
  hipMemsetAsync(gcnt, 0, (size_t)NG * 4, stream);

  int egrid = (E + 255) / 256;
  if (egrid > 2048) egrid = 2048;
  k_edge_count<<<egrid, 256, 0, stream>>>(ei, E, deg);
  k_scan_a<<<nsb, 1024, 0, stream>>>(deg, offs, part, N);
  k_scan_b<<<1, 1024, 0, stream>>>(part, nsb);
  k_scan_c<<<(N + 255) / 256, 256, 0, stream>>>(offs, part, N);
  hipMemsetAsync(deg, 0, (size_t)N * 4, stream);  // cursor
  k_edge_fill<<<egrid, 256, 0, stream>>>(ei, E, offs, deg, csr);

  int ntiles = (N + 31) / 32;
  int ggrid = ntiles < 512 ? ntiles : 512;
  int agrid = (N + 3) / 4;

  k_gemm<<<ggrid, 512, 0, stream>>>(x, W1, as1, ad1, hbf, asb, adb, N, ntiles);
  k_gat_agg<<<agrid, 256, 0, stream>>>(offs, csr, asb, adb, (const uint4*)hbf, b1, g1, be1, xb, HID, N);
  k_gemm<<<ggrid, 512, 0, stream>>>(xb, W2, as2, ad2, hbf, asb, adb, N, ntiles);
  k_gat_agg<<<agrid, 256, 0, stream>>>(offs, csr, asb, adb, (const uint4*)hbf, b2, g2, be2,
                                       (float*)d_out, 256, N);

  k_graph_sum<<<256, 256, 0, stream>>>((const float*)d_out, 256, bat, gsum, gcnt, N);
  int ogrid = (N * 32 + 255) / 256;
  if (ogrid > 4096) ogrid = 4096;
  k_gout<<<ogrid, 256, 0, stream>>>(bat, gsum, gcnt, (float*)d_out, N);
}